// Round 10
// baseline (5791.954 us; speedup 1.0000x reference)
//
#include <hip/hip_runtime.h>
#include <hip/hip_fp16.h>

// B=256, T=512, F=16, H=256, L=2 LSTM + gather(len-1) + ReLU + FC(256->1).
//
// R10: MFMA f16 recurrence, 16 batches/block. Aggregate-L2 fix (R9 showed the
// fused pipeline pinned at ~1.7 TB/s/XCD): 172 streaming blocks -> 32.
//   blocks   0..15 : l0 recurrence, chunk k      (16 batches each, MFMA)
//   blocks  16..31 : l1 recurrence, chunk k-2    (MFMA + precomputed xp1)
//   blocks  32..159: gemm xp1 = W_ih1 @ h0 + b1, chunk k-1 (2 batches each)
// Tc=32, 16 chunks, 18 launches. All cross-role data at kernel boundaries.

#define Tc 32
#define NCHUNK 16

// fp32 region (float offsets)
#define OFF_IH0   0        // Bx frags (halves): [4 g][16 U][64 l][8 j] (64 KB)
#define OFF_B0    16384    // [256 u][4 g] = b_ih0+b_hh0
#define OFF_B1    17408    // [256 u][4 g] = b_ih1+b_hh1
#define OFF_C0S   18432    // [258][256] l0 cell state
#define OFF_C1S   84480    // [258][256] l1 cell state
#define OFF_H1S   150528   // [258][256] l1 h state (fp32)
#define OFF_HLAST 216576   // [258][256]
#define FP_END    282624
// fp16 region (half offsets from h16 = (half*)(ws+FP_END))
#define H_HH0  0           // B-frags: [4 g][16 U][8 ks][64 lane][8 j]
#define H_HH1  262144      // same layout
#define H_IH1  524288      // gemm layout: [128 p][256 u][4 g][2]
#define H_H0C  786432      // [2 slot][258 b][32 t][256 u]
#define H0SLOT 2113536
#define H_XP1  5013504     // [2 slot][16 G][32 t][256 u][16 m][4 g]
#define XPSLOT 8454144
// end 21921792 halves; total ws ~= 45.0 MB (same as R6-R9)

#define SMEM_BYTES 32768   // gemm hc2 32 KB; l0 18 KB; l1 16 KB

typedef _Float16 v8h __attribute__((ext_vector_type(8)));
typedef float v4f __attribute__((ext_vector_type(4)));

__device__ __forceinline__ unsigned packh2(float a, float b) {
  __half2 h = __floats2half2_rn(a, b);
  return *(unsigned*)&h;
}
__device__ __forceinline__ float sigf(float x) {
  return __fdividef(1.f, 1.f + __expf(-x));
}
__device__ __forceinline__ float tanhf_fast(float x) {
  float ax = fabsf(x);
  float e = __expf(-2.f * ax);
  float t = __fdividef(1.f - e, 1.f + e);
  return copysignf(t, x);
}
__device__ __forceinline__ float h2f(unsigned short s) {
  __half h = __builtin_bit_cast(__half, s);
  return __half2float(h);
}
__device__ __forceinline__ float h_at(uint4 v, int i) {
  unsigned wd = ((const unsigned*)&v)[i >> 1];
  unsigned short s = (i & 1) ? (unsigned short)(wd >> 16) : (unsigned short)wd;
  return h2f(s);
}

typedef _Float16 v2h __attribute__((ext_vector_type(2)));

__global__ __launch_bounds__(256) void prep_kernel(
    const float* __restrict__ w_ih0, const float* __restrict__ w_hh0,
    const float* __restrict__ b_ih0, const float* __restrict__ b_hh0,
    const float* __restrict__ w_ih1, const float* __restrict__ w_hh1,
    const float* __restrict__ b_ih1, const float* __restrict__ b_hh1,
    float* __restrict__ ws) {
  const int idx = blockIdx.x * blockDim.x + threadIdx.x;  // [0,131072)
  unsigned* h16u = (unsigned*)(ws + FP_END);
  // w_hh0 / w_hh1 -> MFMA B-fragment layout (half-pair idx = idx)
  {
    const int q2 = idx * 2;
    const int j = q2 & 7, l = (q2 >> 3) & 63, ks = (q2 >> 9) & 7;
    const int U = (q2 >> 12) & 15, g = q2 >> 16;
    const int row = g * 256 + U * 16 + (l & 15);        // gate row (n)
    const int k0 = ks * 32 + ((l >> 4) & 3) * 8 + j;    // k
    h16u[H_HH0 / 2 + idx] =
        packh2(w_hh0[row * 256 + k0], w_hh0[row * 256 + k0 + 1]);
    h16u[H_HH1 / 2 + idx] =
        packh2(w_hh1[row * 256 + k0], w_hh1[row * 256 + k0 + 1]);
  }
  // w_ih1 -> gemm layout [p][u][g][2]
  {
    const int g = idx & 3, u = (idx >> 2) & 255, p = idx >> 10;
    const int j = g * 256 + u;
    h16u[H_IH1 / 2 + idx] =
        packh2(w_ih1[j * 256 + 2 * p], w_ih1[j * 256 + 2 * p + 1]);
  }
  if (idx < 16384) {  // w_ih0 -> padded (K=32) B-frag, one slice
    const int q2 = idx * 2;
    const int j = q2 & 7, l = (q2 >> 3) & 63, U = (q2 >> 9) & 15, g = q2 >> 13;
    const int row = g * 256 + U * 16 + (l & 15);
    const int k0 = (l >> 4) * 8 + j;
    float a = (k0 < 16) ? w_ih0[row * 16 + k0] : 0.f;
    float b = (k0 + 1 < 16) ? w_ih0[row * 16 + k0 + 1] : 0.f;
    ((unsigned*)(ws + OFF_IH0))[idx] = packh2(a, b);
  }
  if (idx < 1024) {  // idx = u*4+g
    const int j = (idx & 3) * 256 + (idx >> 2);
    ws[OFF_B0 + idx] = b_ih0[j] + b_hh0[j];
    ws[OFF_B1 + idx] = b_ih1[j] + b_hh1[j];
  }
}

__global__ __launch_bounds__(1024) void fused_kernel(
    float* __restrict__ ws, const float* __restrict__ x,
    const int* __restrict__ lengths, int step) {
  extern __shared__ __align__(16) char smem_raw[];
  const int bid = blockIdx.x;
  const int tid = threadIdx.x;
  __half* h16 = (__half*)(ws + FP_END);
  unsigned short* h0cS = (unsigned short*)(h16 + H_H0C);
  unsigned short* xpS = (unsigned short*)(h16 + H_XP1);

  if (bid < 32) {
    // =========== roles: l0 (bid<16, chunk=step) / l1 (chunk=step-2) =======
    const bool isL0 = (bid < 16);
    int kc;
    if (isL0) { if (step >= NCHUNK) return; kc = step; }
    else { if (step < 2 || step >= NCHUNK + 2) return; kc = step - 2; }
    const int G = isL0 ? bid : (bid - 16);
    const int bg = G * 16;
    const int w = tid >> 6, l = tid & 63;
    const int n = l & 15, m0 = (l >> 4) * 4;
    const int u = w * 16 + n;  // this lane's hidden unit (C col)
    unsigned short* hf = (unsigned short*)smem_raw;  // [2][8 ks][64 l][8 j]
    unsigned short* xf = hf + 8192;                  // [2][64 l][8 j] (l0)

    int tmaxb = 1;
    for (int i = 0; i < 16; ++i) tmaxb = max(tmaxb, lengths[bg + i]);
    if (kc * Tc >= tmaxb) return;
    const int tend = min(Tc, tmaxb - kc * Tc);
    const int slot = kc & 1, slotP = slot ^ 1;

    const float4* WB =
        (const float4*)(h16 + (isL0 ? H_HH0 : H_HH1));  // B-frag entries
    // frag write position for element (m, k=u):
    const int ksp = u >> 5, lp0 = ((u >> 3) & 3) * 16, jh = u & 7;

    float bias[4];
    v8h bx[4];
    if (isL0) {
      const float4* WX = (const float4*)(ws + OFF_IH0);
      #pragma unroll
      for (int g = 0; g < 4; ++g) {
        bx[g] = __builtin_bit_cast(v8h, WX[(g * 16 + w) * 64 + l]);
        bias[g] = ws[OFF_B0 + u * 4 + g];
      }
    }
    int len4[4];
    #pragma unroll
    for (int r = 0; r < 4; ++r) len4[r] = lengths[bg + m0 + r];

    float c4[4] = {0.f, 0.f, 0.f, 0.f};
    float h4[4] = {0.f, 0.f, 0.f, 0.f};
    // init h-frag buffer 0 with h[t0-1]
    #pragma unroll
    for (int r = 0; r < 4; ++r) {
      unsigned short hv = 0;
      if (kc > 0) {
        if (isL0) {
          hv = h0cS[(size_t)slotP * H0SLOT +
                    ((size_t)(bg + m0 + r) * 32 + 31) * 256 + u];
          c4[r] = ws[OFF_C0S + (bg + m0 + r) * 256 + u];
        } else {
          hv = __half_as_ushort(
              __float2half(ws[OFF_H1S + (bg + m0 + r) * 256 + u]));
          c4[r] = ws[OFF_C1S + (bg + m0 + r) * 256 + u];
        }
      }
      hf[(ksp * 64 + lp0 + m0 + r) * 8 + jh] = hv;
    }
    const unsigned short* xpb = nullptr;
    uint4 q0, q1;
    if (isL0) {
      if (w == 0) {  // x-frag: zero pad region (both bufs) + stage t0
        if (l >= 32) {
          uint4 z = {0, 0, 0, 0};
          *(uint4*)(xf + l * 8) = z;
          *(uint4*)(xf + (64 + l) * 8) = z;
        } else {
          const float* xp =
              x + (size_t)(bg + (l & 15)) * 8192 + (kc * Tc) * 16 + (l >> 4) * 8;
          float4 a = *(const float4*)xp, b = *(const float4*)(xp + 4);
          uint4 v = {packh2(a.x, a.y), packh2(a.z, a.w), packh2(b.x, b.y),
                     packh2(b.z, b.w)};
          *(uint4*)(xf + l * 8) = v;
        }
      }
    } else {  // l1: xp1 base + first-step load
      xpb = xpS + (size_t)slot * XPSLOT + (size_t)G * 524288 + u * 64 + m0 * 4;
      q0 = *(const uint4*)(xpb);
      q1 = *(const uint4*)(xpb + 8);
    }
    // preload B slice 0
    v8h bf[4], bn[4];
    #pragma unroll
    for (int g = 0; g < 4; ++g)
      bf[g] = __builtin_bit_cast(v8h, WB[((g * 16 + w) * 8 + 0) * 64 + l]);
    __syncthreads();

    for (int tc = 0; tc < tend; ++tc) {
      const int cur = tc & 1, nxt = cur ^ 1;
      v4f A[4];
      uint4 p0n, p1n;
      if (isL0) {
        #pragma unroll
        for (int g = 0; g < 4; ++g) {
          v4f bz = {bias[g], bias[g], bias[g], bias[g]};
          A[g] = bz;
        }
        v8h ax = __builtin_bit_cast(v8h, *(const float4*)(xf + (cur * 64 + l) * 8));
        #pragma unroll
        for (int g = 0; g < 4; ++g)
          A[g] = __builtin_amdgcn_mfma_f32_16x16x32_f16(ax, bx[g], A[g], 0, 0, 0);
      } else {
        if (tc + 1 < tend) {  // prefetch next step's xp1
          p0n = *(const uint4*)(xpb + (size_t)(tc + 1) * 16384);
          p1n = *(const uint4*)(xpb + (size_t)(tc + 1) * 16384 + 8);
        }
        #pragma unroll
        for (int g = 0; g < 4; ++g) {
          v4f av;
          av[0] = h_at(q0, g);
          av[1] = h_at(q0, 4 + g);
          av[2] = h_at(q1, g);
          av[3] = h_at(q1, 4 + g);
          A[g] = av;
        }
      }
      // 8 K-slices of the recurrent matmul
      #pragma unroll
      for (int ks = 0; ks < 8; ++ks) {
        if (ks < 7) {
          #pragma unroll
          for (int g = 0; g < 4; ++g)
            bn[g] = __builtin_bit_cast(
                v8h, WB[((g * 16 + w) * 8 + ks + 1) * 64 + l]);
        }
        v8h ah = __builtin_bit_cast(
            v8h, *(const float4*)(hf + ((cur * 8 + ks) * 64 + l) * 8));
        #pragma unroll
        for (int g = 0; g < 4; ++g)
          A[g] = __builtin_amdgcn_mfma_f32_16x16x32_f16(ah, bf[g], A[g], 0, 0, 0);
        #pragma unroll
        for (int g = 0; g < 4; ++g) bf[g] = bn[g];
      }
      // gate tail: lane owns (unit u, batches m0..m0+3)
      #pragma unroll
      for (int r = 0; r < 4; ++r) {
        float ig = sigf(A[0][r]), fg = sigf(A[1][r]);
        float gg = tanhf_fast(A[2][r]), og = sigf(A[3][r]);
        c4[r] = fg * c4[r] + ig * gg;
        h4[r] = og * tanhf_fast(c4[r]);
        unsigned short hv = __half_as_ushort(__float2half(h4[r]));
        hf[((nxt * 8 + ksp) * 64 + lp0 + m0 + r) * 8 + jh] = hv;
        if (isL0) {
          h0cS[(size_t)slot * H0SLOT +
               ((size_t)(bg + m0 + r) * 32 + tc) * 256 + u] = hv;
        } else {
          if (kc * Tc + tc == len4[r] - 1)
            ws[OFF_HLAST + (bg + m0 + r) * 256 + u] = h4[r];
        }
      }
      if (isL0) {
        if (w == 0 && l < 32) {  // stage x-frag for t+1
          int tn = min(kc * Tc + tc + 1, 511);
          const float* xp =
              x + (size_t)(bg + (l & 15)) * 8192 + tn * 16 + (l >> 4) * 8;
          float4 a = *(const float4*)xp, b = *(const float4*)(xp + 4);
          uint4 v = {packh2(a.x, a.y), packh2(a.z, a.w), packh2(b.x, b.y),
                     packh2(b.z, b.w)};
          *(uint4*)(xf + (nxt * 64 + l) * 8) = v;
        }
      } else {
        q0 = p0n;
        q1 = p1n;
      }
      // prefetch B slice 0 for the next step (drains during the barrier)
      #pragma unroll
      for (int g = 0; g < 4; ++g)
        bf[g] = __builtin_bit_cast(v8h, WB[((g * 16 + w) * 8 + 0) * 64 + l]);
      __syncthreads();
    }
    // save state
    #pragma unroll
    for (int r = 0; r < 4; ++r) {
      if (isL0) {
        ws[OFF_C0S + (bg + m0 + r) * 256 + u] = c4[r];
      } else {
        ws[OFF_C1S + (bg + m0 + r) * 256 + u] = c4[r];
        ws[OFF_H1S + (bg + m0 + r) * 256 + u] = h4[r];
      }
    }

  } else {
    // ===== role: gemm xp1 = W_ih1 @ h0 + b1, chunk kc = step-1 ============
    if (step < 1 || step >= NCHUNK + 1) return;
    if (bid >= 160) return;
    const int kc = step - 1;
    const int gid = bid - 32;   // [0,128)
    const int bg2 = gid * 2;    // 2 batches per block
    const int G = bg2 >> 4, mb = bg2 & 15;
    __half2* hc2 = (__half2*)smem_raw;  // [128 p][64 col]

    int lmax = max(lengths[bg2], lengths[bg2 + 1]);
    if (kc * Tc >= lmax) return;
    const int slot = kc & 1;

    {  // stage hc2[p][col] = h0 k-pairs; col = b_loc*32 + t
      const unsigned short* src =
          h0cS + (size_t)slot * H0SLOT + (size_t)bg2 * 8192;
      const int cl = tid & 63, pg = tid >> 6;  // pg in [0,16): 8 p's each
      #pragma unroll
      for (int pp = 0; pp < 8; pp += 4) {
        const int p0 = pg * 8 + pp;
        uint4 v = *(const uint4*)(src + (size_t)cl * 256 + p0 * 2);
        unsigned* d = (unsigned*)hc2;
        d[(p0 + 0) * 64 + cl] = v.x;
        d[(p0 + 1) * 64 + cl] = v.y;
        d[(p0 + 2) * 64 + cl] = v.z;
        d[(p0 + 3) * 64 + cl] = v.w;
      }
    }
    __syncthreads();

    const __half* Wb = h16 + H_IH1;  // [p][u][g][2]
    unsigned short* xdst =
        xpS + (size_t)slot * XPSLOT + (size_t)G * 524288;
    const int rp = tid >> 9, rt = tid & 63, wv = (tid >> 6) & 7;
    const int uA = rp * 128 + rt, uB = uA + 64;
    const int c0 = wv * 8;
    const float4 bA = ((const float4*)(ws + OFF_B1))[uA];
    const float4 bB = ((const float4*)(ws + OFF_B1))[uB];
    float accA[4][8], accB[4][8];
    #pragma unroll
    for (int g = 0; g < 4; ++g)
      #pragma unroll
      for (int cc = 0; cc < 8; ++cc) {
        accA[g][cc] = ((const float*)&bA)[g];
        accB[g][cc] = ((const float*)&bB)[g];
      }
    #pragma unroll 2
    for (int p = 0; p < 128; ++p) {
      float4 wA = *(const float4*)(Wb + (size_t)p * 2048 + uA * 8);
      float4 wB = *(const float4*)(Wb + (size_t)p * 2048 + uB * 8);
      float4 h0v = *(const float4*)(hc2 + p * 64 + c0);      // cols c0..c0+3
      float4 h1v = *(const float4*)(hc2 + p * 64 + c0 + 4);  // cols +4..+7
      const v2h* ga = (const v2h*)&wA;
      const v2h* gb = (const v2h*)&wB;
      const v2h* hv = (const v2h*)&h0v;
      const v2h* hw = (const v2h*)&h1v;
      #pragma unroll
      for (int g = 0; g < 4; ++g) {
        #pragma unroll
        for (int cc = 0; cc < 4; ++cc) {
          accA[g][cc] = __builtin_amdgcn_fdot2(ga[g], hv[cc], accA[g][cc], false);
          accA[g][cc + 4] = __builtin_amdgcn_fdot2(ga[g], hw[cc], accA[g][cc + 4], false);
          accB[g][cc] = __builtin_amdgcn_fdot2(gb[g], hv[cc], accB[g][cc], false);
          accB[g][cc + 4] = __builtin_amdgcn_fdot2(gb[g], hw[cc], accB[g][cc + 4], false);
        }
      }
    }
    #pragma unroll
    for (int cc = 0; cc < 8; ++cc) {
      const int col = c0 + cc;
      const int t = col & 31, m = mb + (col >> 5);
      const size_t base = ((size_t)t * 256) * 64 + (size_t)m * 4;  // halves
      ushort4 oA, oB;
      oA.x = __half_as_ushort(__float2half(accA[0][cc]));
      oA.y = __half_as_ushort(__float2half(accA[1][cc]));
      oA.z = __half_as_ushort(__float2half(accA[2][cc]));
      oA.w = __half_as_ushort(__float2half(accA[3][cc]));
      oB.x = __half_as_ushort(__float2half(accB[0][cc]));
      oB.y = __half_as_ushort(__float2half(accB[1][cc]));
      oB.z = __half_as_ushort(__float2half(accB[2][cc]));
      oB.w = __half_as_ushort(__float2half(accB[3][cc]));
      *(ushort4*)(xdst + base + (size_t)uA * 64) = oA;
      *(ushort4*)(xdst + base + (size_t)uB * 64) = oB;
    }
  }
}

__global__ __launch_bounds__(256) void fc_kernel(
    const float* __restrict__ ws, const float* __restrict__ fc_w,
    const float* __restrict__ fc_b, float* __restrict__ out) {
  __shared__ float red[256];
  const int tid = threadIdx.x;
  const int b = blockIdx.x;
  red[tid] = fmaxf(ws[OFF_HLAST + b * 256 + tid], 0.f) * fc_w[tid];
  __syncthreads();
  #pragma unroll
  for (int s = 128; s > 0; s >>= 1) {
    if (tid < s) red[tid] += red[tid + s];
    __syncthreads();
  }
  if (tid == 0) out[b] = red[0] + fc_b[0];
}

extern "C" void kernel_launch(void* const* d_in, const int* in_sizes, int n_in,
                              void* d_out, int out_size, void* d_ws, size_t ws_size,
                              hipStream_t stream) {
  const float* x     = (const float*)d_in[0];
  const int*   lens  = (const int*)d_in[1];
  const float* w_ih0 = (const float*)d_in[2];
  const float* w_hh0 = (const float*)d_in[3];
  const float* b_ih0 = (const float*)d_in[4];
  const float* b_hh0 = (const float*)d_in[5];
  const float* w_ih1 = (const float*)d_in[6];
  const float* w_hh1 = (const float*)d_in[7];
  const float* b_ih1 = (const float*)d_in[8];
  const float* b_hh1 = (const float*)d_in[9];
  const float* fc_w  = (const float*)d_in[10];
  const float* fc_b  = (const float*)d_in[11];
  float* out = (float*)d_out;
  float* ws  = (float*)d_ws;

  hipLaunchKernelGGL(prep_kernel, dim3(512), dim3(256), 0, stream,
                     w_ih0, w_hh0, b_ih0, b_hh0, w_ih1, w_hh1, b_ih1, b_hh1, ws);
  hipFuncSetAttribute(reinterpret_cast<const void*>(fused_kernel),
                      hipFuncAttributeMaxDynamicSharedMemorySize, SMEM_BYTES);
  for (int k = 0; k < NCHUNK + 2; ++k) {
    hipLaunchKernelGGL(fused_kernel, dim3(160), dim3(1024), SMEM_BYTES, stream,
                       ws, x, lens, k);
  }
  hipLaunchKernelGGL(fc_kernel, dim3(256), dim3(256), 0, stream,
                     ws, fc_w, fc_b, out);
}